// Round 2
// baseline (79.043 us; speedup 1.0000x reference)
//
#include <hip/hip_runtime.h>

// ArithmeticCompute: circle-encoded modular arithmetic over PRIMES.
// out[3][B*S][10][2] = {add, sub, mul} on the unit circle.
//
// Work unit = (pair-group of 64, prime): exactly one wave. Units are numbered
// unit = pg*10 + pi, so the 4 waves of a block carry DIFFERENT primes ->
// block runtimes are mixed (load balance via dispatcher replacement).
// Register diet: only eb[P] + W[P] live through the hot loop; the a-side
// softmax is recomputed per-i (2 FMA + exp) instead of stored.

#define SOFTMAX_TEMP 1000.0f

constexpr double PI_D = 3.14159265358979323846264338327950288;

constexpr double tay_cos(double x) {
    double x2 = x * x, term = 1.0, sum = 1.0;
    for (int k = 1; k <= 15; ++k) { term *= -x2 / double((2 * k - 1) * (2 * k)); sum += term; }
    return sum;
}
constexpr double tay_sin(double x) {
    double x2 = x * x, term = x, sum = x;
    for (int k = 1; k <= 15; ++k) { term *= -x2 / double((2 * k) * (2 * k + 1)); sum += term; }
    return sum;
}

template <int P> struct Tab { float c[P]; float s[P]; };

template <int P>
constexpr Tab<P> make_tab() {
    Tab<P> t{};
    for (int r = 0; r < P; ++r) {
        double x = 2.0 * PI_D * double(r) / double(P);
        if (x > PI_D) x -= 2.0 * PI_D;
        t.c[r] = (float)tay_cos(x);
        t.s[r] = (float)tay_sin(x);
    }
    return t;
}

template <int P>
__device__ __forceinline__ void mul_prime(float ca, float sa, float cb, float sb,
                                          float& oc, float& os) {
    constexpr Tab<P> T = make_tab<P>();

    // Pass 1: maxes for both sides (nothing stored).
    float ma = -1e30f, mb = -1e30f;
#pragma unroll
    for (int r = 0; r < P; ++r) {
        ma = fmaxf(ma, ca * T.c[r] + sa * T.s[r]);
        mb = fmaxf(mb, cb * T.c[r] + sb * T.s[r]);
    }

    // Pass 2: b-side softmax numerators (stored) + sum.
    float eb[P];
    float Sb = 0.f;
#pragma unroll
    for (int r = 0; r < P; ++r) {
        float x = __expf(SOFTMAX_TEMP * (cb * T.c[r] + sb * T.s[r] - mb));
        eb[r] = x; Sb += x;
    }

    // Pass 3: residue histogram W[k] = sum_{(i*j)%P==k} ea[i]*eb[j].
    // ea recomputed on the fly; i=0 row and j=0 column folded in closed form.
    float W[P];
#pragma unroll
    for (int k = 0; k < P; ++k) W[k] = 0.f;

    float Sa = 0.f, ea0 = 0.f;
#pragma unroll
    for (int i = 0; i < P; ++i) {
        float ea_i = __expf(SOFTMAX_TEMP * (ca * T.c[i] + sa * T.s[i] - ma));
        Sa += ea_i;
        if (i == 0) { ea0 = ea_i; }
        else {
#pragma unroll
            for (int j = 1; j < P; ++j) {
                const int k = (i * j) % P;  // compile-time after unroll
                W[k] = fmaf(ea_i, eb[j], W[k]);
            }
        }
    }
    // i==0 row: ea0*eb[j] for all j -> k=0; j==0 col for i>=1: eb[0]*(Sa-ea0).
    W[0] += ea0 * Sb + eb[0] * (Sa - ea0);

    float accC = 0.f, accS = 0.f;
#pragma unroll
    for (int k = 0; k < P; ++k) {
        accC = fmaf(W[k], T.c[k], accC);
        accS = fmaf(W[k], T.s[k], accS);
    }
    const float inv = 1.0f / (Sa * Sb);
    oc = accC * inv;
    os = accS * inv;
}

__global__ __launch_bounds__(256) void arith_kernel(const float* __restrict__ a,
                                                    const float* __restrict__ b,
                                                    float* __restrict__ out,
                                                    int n_pairs, int n_units) {
    const int lane = threadIdx.x & 63;
    const int unit = blockIdx.x * 4 + (threadIdx.x >> 6);
    if (unit >= n_units) return;
    const int pg = unit / 10;      // pair group
    const int pi = unit - pg * 10; // prime index (wave-uniform)
    const int pair = pg * 64 + lane;
    if (pair >= n_pairs) return;

    const int base = pair * 20 + pi * 2;
    const float2 av = *(const float2*)(a + base);
    const float2 bv = *(const float2*)(b + base);
    const float ca = av.x, sa = av.y, cb = bv.x, sb = bv.y;

    // add: angles add -> complex multiply; sub: a * conj(b).
    const float pcc = ca * cb, pss = sa * sb, psc = sa * cb, pcs = ca * sb;
    const int plane = n_pairs * 20;
    *(float2*)(out + base)         = make_float2(pcc - pss, psc + pcs);
    *(float2*)(out + plane + base) = make_float2(pcc + pss, psc - pcs);

    float oc, os;
    switch (pi) {
        case 0: mul_prime<2>(ca, sa, cb, sb, oc, os); break;
        case 1: mul_prime<3>(ca, sa, cb, sb, oc, os); break;
        case 2: mul_prime<5>(ca, sa, cb, sb, oc, os); break;
        case 3: mul_prime<7>(ca, sa, cb, sb, oc, os); break;
        case 4: mul_prime<11>(ca, sa, cb, sb, oc, os); break;
        case 5: mul_prime<13>(ca, sa, cb, sb, oc, os); break;
        case 6: mul_prime<17>(ca, sa, cb, sb, oc, os); break;
        case 7: mul_prime<19>(ca, sa, cb, sb, oc, os); break;
        case 8: mul_prime<23>(ca, sa, cb, sb, oc, os); break;
        default: mul_prime<29>(ca, sa, cb, sb, oc, os); break;
    }
    *(float2*)(out + 2 * plane + base) = make_float2(oc, os);
}

extern "C" void kernel_launch(void* const* d_in, const int* in_sizes, int n_in,
                              void* d_out, int out_size, void* d_ws, size_t ws_size,
                              hipStream_t stream) {
    const float* a = (const float*)d_in[0];
    const float* b = (const float*)d_in[1];
    float* out = (float*)d_out;
    const int n_pairs = in_sizes[0] / 20;               // B*S = 65536
    const int n_groups = (n_pairs + 63) / 64;           // 1024
    const int n_units = n_groups * 10;                  // 10240 waves
    const int n_blocks = (n_units + 3) / 4;             // 4 waves per block

    dim3 block(256);
    dim3 grid(n_blocks);
    arith_kernel<<<grid, block, 0, stream>>>(a, b, out, n_pairs, n_units);
}